// Round 1
// baseline (1792.839 us; speedup 1.0000x reference)
//
#include <hip/hip_runtime.h>
#include <math.h>

#define BB 8
#define LL 2048
#define DD 128
#define GG 8
#define NRR 16   // state rows per workgroup in recurrence

// ---------------------------------------------------------------------------
// Generic C[M,O] = X[M,128] @ W[O,128]^T, optional sigmoid epilogue.
// grid (M/32, O/64), block 256. LDS-tiled, fp32 vector FMA.
// ---------------------------------------------------------------------------
__global__ __launch_bounds__(256) void gemm_kernel(
    const float* __restrict__ X, int ldx,
    const float* __restrict__ W,
    float* __restrict__ C, int ldc,
    int applySig)
{
    __shared__ float Xs[32 * 132];
    __shared__ float Ws[64 * 132];
    const int tid = threadIdx.x;
    const int m0 = blockIdx.x * 32;
    const int o0 = blockIdx.y * 64;
    {
        int row = tid >> 3, cg = tid & 7;
        const float* src = X + (size_t)(m0 + row) * ldx + cg * 16;
        float* dst = Xs + row * 132 + cg * 16;
#pragma unroll
        for (int u = 0; u < 4; ++u)
            *(float4*)(dst + 4 * u) = *(const float4*)(src + 4 * u);
    }
    {
        int o = tid >> 2, cg = tid & 3;
        const float* src = W + (size_t)(o0 + o) * 128 + cg * 32;
        float* dst = Ws + o * 132 + cg * 32;
#pragma unroll
        for (int u = 0; u < 8; ++u)
            *(float4*)(dst + 4 * u) = *(const float4*)(src + 4 * u);
    }
    __syncthreads();
    const int tx = tid & 31, ty = tid >> 5;
    float acc[4][2] = {};
    const float* xb = Xs + (ty * 4) * 132;
    const float* wb = Ws + (tx * 2) * 132;
    for (int k0 = 0; k0 < 128; k0 += 4) {
        float4 xr[4], wr[2];
#pragma unroll
        for (int r = 0; r < 4; ++r) xr[r] = *(const float4*)(xb + r * 132 + k0);
#pragma unroll
        for (int cc = 0; cc < 2; ++cc) wr[cc] = *(const float4*)(wb + cc * 132 + k0);
#pragma unroll
        for (int r = 0; r < 4; ++r)
#pragma unroll
            for (int cc = 0; cc < 2; ++cc) {
                acc[r][cc] += xr[r].x * wr[cc].x + xr[r].y * wr[cc].y
                            + xr[r].z * wr[cc].z + xr[r].w * wr[cc].w;
            }
    }
#pragma unroll
    for (int r = 0; r < 4; ++r)
#pragma unroll
        for (int cc = 0; cc < 2; ++cc) {
            float v = acc[r][cc];
            if (applySig) v = 1.0f / (1.0f + __expf(-v));
            C[(size_t)(m0 + ty * 4 + r) * ldc + o0 + tx * 2 + cc] = v;
        }
}

// ---------------------------------------------------------------------------
// Depthwise conv(K=3, pad 1) + sigmoid + L2-normalize over D for q and k.
// One wave per (b,l); lane handles dims d0 = 2*lane, 2*lane+1.
// q raw = qkv cols [0,128); k raw = qkv cols [128,256).
// ---------------------------------------------------------------------------
__global__ __launch_bounds__(256) void convnorm_kernel(
    const float* __restrict__ qkv,
    const float* __restrict__ qw, const float* __restrict__ qb,
    const float* __restrict__ kw, const float* __restrict__ kb,
    float* __restrict__ qn, float* __restrict__ kn)
{
    const int tid = threadIdx.x;
    const int lane = tid & 63;
    const int wid = tid >> 6;
    const int m = blockIdx.x * 4 + wid;     // b*L + l
    const int l = m & (LL - 1);
    const int d0 = lane * 2;
    float yq0 = qb[d0], yq1 = qb[d0 + 1];
    float yk0 = kb[d0], yk1 = kb[d0 + 1];
#pragma unroll
    for (int tau = 0; tau < 3; ++tau) {
        int lp = l + tau - 1;
        if (lp >= 0 && lp < LL) {
            const float* base = qkv + (size_t)(m + tau - 1) * 512;
            yq0 += base[d0]       * qw[d0 * 3 + tau];
            yq1 += base[d0 + 1]   * qw[(d0 + 1) * 3 + tau];
            yk0 += base[128 + d0]     * kw[d0 * 3 + tau];
            yk1 += base[128 + d0 + 1] * kw[(d0 + 1) * 3 + tau];
        }
    }
    yq0 = 1.0f / (1.0f + __expf(-yq0));
    yq1 = 1.0f / (1.0f + __expf(-yq1));
    yk0 = 1.0f / (1.0f + __expf(-yk0));
    yk1 = 1.0f / (1.0f + __expf(-yk1));
    float sq = yq0 * yq0 + yq1 * yq1;
    float sk = yk0 * yk0 + yk1 * yk1;
#pragma unroll
    for (int msk = 1; msk <= 32; msk <<= 1) {
        sq += __shfl_xor(sq, msk);
        sk += __shfl_xor(sk, msk);
    }
    float rq = 1.0f / fmaxf(sqrtf(sq), 1e-12f);
    float rk = 1.0f / fmaxf(sqrtf(sk), 1e-12f);
    size_t o = (size_t)m * DD + d0;
    qn[o] = yq0 * rq; qn[o + 1] = yq1 * rq;
    kn[o] = yk0 * rk; kn[o + 1] = yk1 * rk;
}

// ---------------------------------------------------------------------------
// Sequential delta-rule recurrence. Grid 64 = B*G workgroups of 256 threads.
// Each WG owns NRR=16 state rows of one batch in registers, in TWO layouts:
//   A: thread(iA=tid/16, c=tid%16) holds S[iA][c*8 .. c*8+7]  (for Sk matvec)
//   B: thread(jB=tid%128, rh=tid/128) holds S[rh*8 .. rh*8+7][jB] (for q^T S)
// Per step: one __syncthreads(). Vectors staged via multi-buffered LDS with
// one-step global prefetch. Partial outputs -> pout[G][B*L*D].
// ---------------------------------------------------------------------------
__global__ __launch_bounds__(256) void recur_kernel(
    const float* __restrict__ qn, const float* __restrict__ kn,
    const float* __restrict__ qkv, const float* __restrict__ ab,
    const float* __restrict__ state,
    float* __restrict__ pout, float* __restrict__ sfin)
{
    __shared__ float s_kab[3][384];   // [buf][k(128), a(128), b(128)]
    __shared__ float s_sk[2][NRR];
    __shared__ float s_v[2][NRR];
    __shared__ float s_q[2][NRR];
    __shared__ float s_po[2][256];

    const int tid = threadIdx.x;
    const int b = blockIdx.x >> 3;
    const int g = blockIdx.x & 7;
    const int rbase = g * NRR;
    const int iA = tid >> 4;
    const int c = tid & 15;
    const int colA = c * 8;
    const int jB = tid & 127;
    const int rh = tid >> 7;
    const size_t mb = (size_t)b * LL;

    float SA[8], SB[8];
    {
        const float* sp = state + ((size_t)b * DD + rbase + iA) * DD + colA;
        float4 a0 = *(const float4*)sp;
        float4 a1 = *(const float4*)(sp + 4);
        SA[0] = a0.x; SA[1] = a0.y; SA[2] = a0.z; SA[3] = a0.w;
        SA[4] = a1.x; SA[5] = a1.y; SA[6] = a1.z; SA[7] = a1.w;
    }
#pragma unroll
    for (int r = 0; r < 8; ++r)
        SB[r] = state[((size_t)b * DD + rbase + rh * 8 + r) * DD + jB];

    float kA[8];
    {
        const float* kp = kn + mb * DD + colA;   // k[t=0]
        float4 a0 = *(const float4*)kp;
        float4 a1 = *(const float4*)(kp + 4);
        kA[0] = a0.x; kA[1] = a0.y; kA[2] = a0.z; kA[3] = a0.w;
        kA[4] = a1.x; kA[5] = a1.y; kA[6] = a1.z; kA[7] = a1.w;
    }

    float kr = 0, ar = 0, br = 0, vr = 0, qr = 0;
    if (tid < 128) {
        kr = kn[mb * DD + tid];
        ar = ab[mb * 256 + tid];
        br = ab[mb * 256 + 128 + tid];
        s_kab[0][tid] = kr;
        s_kab[0][128 + tid] = ar;
        s_kab[0][256 + tid] = br;
        kr = kn[(mb + 1) * DD + tid];
        ar = ab[(mb + 1) * 256 + tid];
        br = ab[(mb + 1) * 256 + 128 + tid];
    } else if (tid < 128 + NRR) {
        vr = qkv[mb * 512 + 256 + rbase + (tid - 128)];
    } else if (tid < 128 + 2 * NRR) {
        qr = qn[mb * DD + rbase + (tid - 128 - NRR)];
    }

    for (int t = 0; t < LL; ++t) {
        const int b2 = t & 1;
        const int b3c = t % 3;
        const int b3n = (t + 1) % 3;
        // ---- PHASE 0: stage vectors (prefetched regs -> LDS), Sk products ----
        if (tid < 128) {
            s_kab[b3n][tid] = kr;
            s_kab[b3n][128 + tid] = ar;
            s_kab[b3n][256 + tid] = br;
            int t2 = (t + 2 < LL) ? t + 2 : LL - 1;
            kr = kn[(mb + t2) * DD + tid];
            ar = ab[(mb + t2) * 256 + tid];
            br = ab[(mb + t2) * 256 + 128 + tid];
        } else if (tid < 128 + NRR) {
            s_v[b2][tid - 128] = vr;
            int t1 = (t + 1 < LL) ? t + 1 : LL - 1;
            vr = qkv[(mb + t1) * 512 + 256 + rbase + (tid - 128)];
        } else if (tid < 128 + 2 * NRR) {
            s_q[b2][tid - 128 - NRR] = qr;
            int t1 = (t + 1 < LL) ? t + 1 : LL - 1;
            qr = qn[(mb + t1) * DD + rbase + (tid - 128 - NRR)];
        }
        float p = SA[0] * kA[0];
        p = fmaf(SA[1], kA[1], p);
        p = fmaf(SA[2], kA[2], p);
        p = fmaf(SA[3], kA[3], p);
        p = fmaf(SA[4], kA[4], p);
        p = fmaf(SA[5], kA[5], p);
        p = fmaf(SA[6], kA[6], p);
        p = fmaf(SA[7], kA[7], p);
        p += __shfl_xor(p, 1);
        p += __shfl_xor(p, 2);
        p += __shfl_xor(p, 4);
        p += __shfl_xor(p, 8);
        if (c == 0) s_sk[b2][iA] = p;
        __syncthreads();
        // ---- PHASE 1: updates + output partials ----
        {   // copy A update (row iA, cols colA..colA+7); p == Sk[iA]
            const float vA = s_v[b2][iA];
            const float* ap = &s_kab[b3c][128 + colA];
            const float* bp = &s_kab[b3c][256 + colA];
            float4 a0 = *(const float4*)ap, a1 = *(const float4*)(ap + 4);
            float4 bb0 = *(const float4*)bp, bb1 = *(const float4*)(bp + 4);
            float aA[8] = {a0.x, a0.y, a0.z, a0.w, a1.x, a1.y, a1.z, a1.w};
            float bA[8] = {bb0.x, bb0.y, bb0.z, bb0.w, bb1.x, bb1.y, bb1.z, bb1.w};
#pragma unroll
            for (int u = 0; u < 8; ++u) {
                float bk = bA[u] * kA[u];
                float w = fmaf(-aA[u], p, vA) * bk;   // (v_i - a_j*Sk_i)*bk_j
                SA[u] = fmaf(aA[u], SA[u], w);
            }
            const float* kp = &s_kab[b3n][colA];     // k[t+1] for next phase 0
            float4 k0 = *(const float4*)kp, k1 = *(const float4*)(kp + 4);
            kA[0] = k0.x; kA[1] = k0.y; kA[2] = k0.z; kA[3] = k0.w;
            kA[4] = k1.x; kA[5] = k1.y; kA[6] = k1.z; kA[7] = k1.w;
        }
        {   // copy B update (col jB, rows rh*8..rh*8+7) + output partial
            const float kj = s_kab[b3c][jB];
            const float aj = s_kab[b3c][128 + jB];
            const float bj = s_kab[b3c][256 + jB];
            const float bkj = bj * kj;
            float4 sk0 = *(const float4*)&s_sk[b2][rh * 8];
            float4 sk1 = *(const float4*)&s_sk[b2][rh * 8 + 4];
            float4 v0 = *(const float4*)&s_v[b2][rh * 8];
            float4 v1 = *(const float4*)&s_v[b2][rh * 8 + 4];
            float4 q0 = *(const float4*)&s_q[b2][rh * 8];
            float4 q1 = *(const float4*)&s_q[b2][rh * 8 + 4];
            float skv[8] = {sk0.x, sk0.y, sk0.z, sk0.w, sk1.x, sk1.y, sk1.z, sk1.w};
            float vv[8]  = {v0.x, v0.y, v0.z, v0.w, v1.x, v1.y, v1.z, v1.w};
            float qv[8]  = {q0.x, q0.y, q0.z, q0.w, q1.x, q1.y, q1.z, q1.w};
            float pacc = 0.0f;
#pragma unroll
            for (int r = 0; r < 8; ++r) {
                float w = fmaf(-aj, skv[r], vv[r]) * bkj;
                SB[r] = fmaf(aj, SB[r], w);
                pacc = fmaf(qv[r], SB[r], pacc);
            }
            s_po[b2][tid] = pacc;
        }
        if (t > 0 && tid < 128) {   // combine previous step's partials
            int pb = b2 ^ 1;
            float po = s_po[pb][tid] + s_po[pb][128 + tid];
            pout[(size_t)g * (BB * LL * DD) + (mb + (t - 1)) * DD + tid] = po;
        }
    }
    __syncthreads();
    if (tid < 128) {
        int pb = (LL - 1) & 1;
        float po = s_po[pb][tid] + s_po[pb][128 + tid];
        pout[(size_t)g * (BB * LL * DD) + (mb + (LL - 1)) * DD + tid] = po;
    }
    {
        float* sp = sfin + ((size_t)b * DD + rbase + iA) * DD + colA;
        float4 o0 = {SA[0], SA[1], SA[2], SA[3]};
        float4 o1 = {SA[4], SA[5], SA[6], SA[7]};
        *(float4*)sp = o0;
        *(float4*)(sp + 4) = o1;
    }
}

// ---------------------------------------------------------------------------
// out_core = silu(sum_g pout[g])
// ---------------------------------------------------------------------------
__global__ __launch_bounds__(256) void combine_silu_kernel(
    const float* __restrict__ pout, float* __restrict__ oc)
{
    const size_t N = (size_t)BB * LL * DD;
    size_t idx = ((size_t)blockIdx.x * 256 + threadIdx.x) * 4;
    float4 s = {0, 0, 0, 0};
#pragma unroll
    for (int g = 0; g < GG; ++g) {
        float4 pv = *(const float4*)(pout + g * N + idx);
        s.x += pv.x; s.y += pv.y; s.z += pv.z; s.w += pv.w;
    }
    s.x = s.x / (1.0f + __expf(-s.x));
    s.y = s.y / (1.0f + __expf(-s.y));
    s.z = s.z / (1.0f + __expf(-s.z));
    s.w = s.w / (1.0f + __expf(-s.w));
    *(float4*)(oc + idx) = s;
}

// ---------------------------------------------------------------------------
// d_out = y * rsqrt(mean(y^2)+1e-6) * rms_w + residual. One wave per (b,l).
// ---------------------------------------------------------------------------
__global__ __launch_bounds__(256) void rms_res_kernel(
    const float* __restrict__ y, const float* __restrict__ res,
    const float* __restrict__ rmsw, float* __restrict__ out)
{
    const int tid = threadIdx.x;
    const int lane = tid & 63;
    const int wid = tid >> 6;
    const int m = blockIdx.x * 4 + wid;
    const int d0 = lane * 2;
    size_t o = (size_t)m * DD + d0;
    float2 yv = *(const float2*)(y + o);
    float ss = yv.x * yv.x + yv.y * yv.y;
#pragma unroll
    for (int msk = 1; msk <= 32; msk <<= 1) ss += __shfl_xor(ss, msk);
    float r = rsqrtf(ss * (1.0f / 128.0f) + 1e-6f);
    float2 rv = *(const float2*)(res + o);
    out[o]     = yv.x * r * rmsw[d0]     + rv.x;
    out[o + 1] = yv.y * r * rmsw[d0 + 1] + rv.y;
}

// ---------------------------------------------------------------------------
extern "C" void kernel_launch(void* const* d_in, const int* in_sizes, int n_in,
                              void* d_out, int out_size, void* d_ws, size_t ws_size,
                              hipStream_t stream)
{
    const float* x      = (const float*)d_in[0];
    const float* state  = (const float*)d_in[1];
    const float* W_in   = (const float*)d_in[2];
    const float* W_gate = (const float*)d_in[3];
    const float* W_out  = (const float*)d_in[4];
    const float* W_res  = (const float*)d_in[5];
    const float* qcw    = (const float*)d_in[6];
    const float* qcb    = (const float*)d_in[7];
    const float* kcw    = (const float*)d_in[8];
    const float* kcb    = (const float*)d_in[9];
    const float* rmsw   = (const float*)d_in[10];
    float* out  = (float*)d_out;
    float* sfin = out + (size_t)BB * LL * DD;

    const size_t M = (size_t)BB * LL;            // 16384
    float* ws = (float*)d_ws;
    float* qkv = ws;                 ws += M * 512;          // 8.4M f
    float* abv = ws;                 ws += M * 256;          // 4.2M f
    float* res = ws;                 ws += M * DD;
    float* qnb = ws;                 ws += M * DD;
    float* knb = ws;                 ws += M * DD;
    float* po  = ws;                 ws += (size_t)GG * M * DD; // 16.8M f
    float* oc  = ws;                 ws += M * DD;
    float* yb  = ws;                 ws += M * DD;

    dim3 blk(256);
    // qkv = x @ W_in^T  [M,512]
    gemm_kernel<<<dim3(M / 32, 8), blk, 0, stream>>>(x, 128, W_in, qkv, 512, 0);
    // residual = x @ W_res^T [M,128]
    gemm_kernel<<<dim3(M / 32, 2), blk, 0, stream>>>(x, 128, W_res, res, 128, 0);
    // q/k conv + sigmoid + l2norm
    convnorm_kernel<<<dim3(M / 4), blk, 0, stream>>>(qkv, qcw, qcb, kcw, kcb, qnb, knb);
    // alpha/beta = sigmoid(gate @ W_gate^T) [M,256]
    gemm_kernel<<<dim3(M / 32, 4), blk, 0, stream>>>(qkv + 384, 512, W_gate, abv, 256, 1);
    // recurrence
    recur_kernel<<<dim3(BB * GG), blk, 0, stream>>>(qnb, knb, qkv, abv, state, po, sfin);
    // combine partials + silu
    combine_silu_kernel<<<dim3((M * DD) / 1024), blk, 0, stream>>>(po, oc);
    // y = out_core @ W_out^T
    gemm_kernel<<<dim3(M / 32, 2), blk, 0, stream>>>(oc, 128, W_out, yb, 128, 0);
    // RMS + residual -> d_out
    rms_res_kernel<<<dim3(M / 4), blk, 0, stream>>>(yb, res, rmsw, out);
}

// Round 2
// 1368.641 us; speedup vs baseline: 1.3099x; 1.3099x over previous
//
#include <hip/hip_runtime.h>
#include <hip/hip_bf16.h>
#include <math.h>

#define BB 8
#define LL 2048
#define DD 128
#define GG 16   // state-row groups (8 rows per group, one wave each)

// ---------------------------------------------------------------------------
// Generic C[M,O] = X[M,128] @ W[O,128]^T, optional sigmoid epilogue.
// grid (M/32, O/64), block 256. LDS-tiled, fp32 vector FMA.
// ---------------------------------------------------------------------------
__global__ __launch_bounds__(256) void gemm_kernel(
    const float* __restrict__ X, int ldx,
    const float* __restrict__ W,
    float* __restrict__ C, int ldc,
    int applySig)
{
    __shared__ float Xs[32 * 132];
    __shared__ float Ws[64 * 132];
    const int tid = threadIdx.x;
    const int m0 = blockIdx.x * 32;
    const int o0 = blockIdx.y * 64;
    {
        int row = tid >> 3, cg = tid & 7;
        const float* src = X + (size_t)(m0 + row) * ldx + cg * 16;
        float* dst = Xs + row * 132 + cg * 16;
#pragma unroll
        for (int u = 0; u < 4; ++u)
            *(float4*)(dst + 4 * u) = *(const float4*)(src + 4 * u);
    }
    {
        int o = tid >> 2, cg = tid & 3;
        const float* src = W + (size_t)(o0 + o) * 128 + cg * 32;
        float* dst = Ws + o * 132 + cg * 32;
#pragma unroll
        for (int u = 0; u < 8; ++u)
            *(float4*)(dst + 4 * u) = *(const float4*)(src + 4 * u);
    }
    __syncthreads();
    const int tx = tid & 31, ty = tid >> 5;
    float acc[4][2] = {};
    const float* xb = Xs + (ty * 4) * 132;
    const float* wb = Ws + (tx * 2) * 132;
    for (int k0 = 0; k0 < 128; k0 += 4) {
        float4 xr[4], wr[2];
#pragma unroll
        for (int r = 0; r < 4; ++r) xr[r] = *(const float4*)(xb + r * 132 + k0);
#pragma unroll
        for (int cc = 0; cc < 2; ++cc) wr[cc] = *(const float4*)(wb + cc * 132 + k0);
#pragma unroll
        for (int r = 0; r < 4; ++r)
#pragma unroll
            for (int cc = 0; cc < 2; ++cc) {
                acc[r][cc] += xr[r].x * wr[cc].x + xr[r].y * wr[cc].y
                            + xr[r].z * wr[cc].z + xr[r].w * wr[cc].w;
            }
    }
#pragma unroll
    for (int r = 0; r < 4; ++r)
#pragma unroll
        for (int cc = 0; cc < 2; ++cc) {
            float v = acc[r][cc];
            if (applySig) v = 1.0f / (1.0f + __expf(-v));
            C[(size_t)(m0 + ty * 4 + r) * ldc + o0 + tx * 2 + cc] = v;
        }
}

// ---------------------------------------------------------------------------
// Depthwise conv(K=3, pad 1) + sigmoid + L2-normalize over D for q and k.
// Also emits mn = beta * k_norm (beta from ab[:,128:256]).
// One wave per (b,l); lane handles dims d0 = 2*lane, 2*lane+1.
// ---------------------------------------------------------------------------
__global__ __launch_bounds__(256) void convnorm_kernel(
    const float* __restrict__ qkv,
    const float* __restrict__ qw, const float* __restrict__ qb,
    const float* __restrict__ kw, const float* __restrict__ kb,
    const float* __restrict__ ab,
    float* __restrict__ qn, float* __restrict__ kn, float* __restrict__ mn)
{
    const int tid = threadIdx.x;
    const int lane = tid & 63;
    const int wid = tid >> 6;
    const int m = blockIdx.x * 4 + wid;     // b*L + l
    const int l = m & (LL - 1);
    const int d0 = lane * 2;
    float yq0 = qb[d0], yq1 = qb[d0 + 1];
    float yk0 = kb[d0], yk1 = kb[d0 + 1];
#pragma unroll
    for (int tau = 0; tau < 3; ++tau) {
        int lp = l + tau - 1;
        if (lp >= 0 && lp < LL) {
            const float* base = qkv + (size_t)(m + tau - 1) * 512;
            yq0 += base[d0]       * qw[d0 * 3 + tau];
            yq1 += base[d0 + 1]   * qw[(d0 + 1) * 3 + tau];
            yk0 += base[128 + d0]     * kw[d0 * 3 + tau];
            yk1 += base[128 + d0 + 1] * kw[(d0 + 1) * 3 + tau];
        }
    }
    yq0 = 1.0f / (1.0f + __expf(-yq0));
    yq1 = 1.0f / (1.0f + __expf(-yq1));
    yk0 = 1.0f / (1.0f + __expf(-yk0));
    yk1 = 1.0f / (1.0f + __expf(-yk1));
    float sq = yq0 * yq0 + yq1 * yq1;
    float sk = yk0 * yk0 + yk1 * yk1;
#pragma unroll
    for (int msk = 1; msk <= 32; msk <<= 1) {
        sq += __shfl_xor(sq, msk);
        sk += __shfl_xor(sk, msk);
    }
    float rq = 1.0f / fmaxf(sqrtf(sq), 1e-12f);
    float rk = 1.0f / fmaxf(sqrtf(sk), 1e-12f);
    size_t o = (size_t)m * DD + d0;
    float k0n = yk0 * rk, k1n = yk1 * rk;
    qn[o] = yq0 * rq; qn[o + 1] = yq1 * rq;
    kn[o] = k0n;      kn[o + 1] = k1n;
    float b0 = ab[(size_t)m * 256 + 128 + d0];
    float b1 = ab[(size_t)m * 256 + 128 + d0 + 1];
    mn[o] = b0 * k0n; mn[o + 1] = b1 * k1n;
}

// ---------------------------------------------------------------------------
// Barrier-free sequential delta-rule recurrence.
// Grid 128 = B*GG workgroups of 64 threads (ONE wave each).
// Wave (b,g) owns state rows rbase=g*8 .. +8 of batch b, in registers, in
// two layouts:
//   A: lane (iA=lane>>3, c=lane&7) holds S[iA][c*16 .. +16)  -> SA[16]
//      (S·k dot: 3-stage shfl_xor over the 8 lanes of a row group)
//   B: lane holds cols {lane, lane+64} of all 8 rows        -> SB[8][2]
//      (q^T S partial: thread-local FMA)
// No LDS, no __syncthreads: all per-step inputs prefetched one step ahead
// into registers; cross-lane only via shfl. Partials -> pout (bf16).
// ---------------------------------------------------------------------------
__global__ __launch_bounds__(64) void recur_kernel(
    const float* __restrict__ qn, const float* __restrict__ kn,
    const float* __restrict__ mn, const float* __restrict__ ab,
    const float* __restrict__ qkv, const float* __restrict__ state,
    __hip_bfloat16* __restrict__ pout, float* __restrict__ sfin)
{
    const int lane = threadIdx.x;
    const int b = blockIdx.x >> 4;
    const int g = blockIdx.x & (GG - 1);
    const int rbase = g * 8;
    const int iA = lane >> 3;
    const int c = lane & 7;
    const int colA = c * 16;
    const size_t mb = (size_t)b * LL;

    float SA[16];
    {
        const float* sp = state + ((size_t)b * DD + rbase + iA) * DD + colA;
#pragma unroll
        for (int u = 0; u < 4; ++u) {
            float4 t4 = *(const float4*)(sp + 4 * u);
            SA[4 * u + 0] = t4.x; SA[4 * u + 1] = t4.y;
            SA[4 * u + 2] = t4.z; SA[4 * u + 3] = t4.w;
        }
    }
    float SB[8][2];
#pragma unroll
    for (int r = 0; r < 8; ++r) {
        const float* sp = state + ((size_t)b * DD + rbase + r) * DD + lane;
        SB[r][0] = sp[0]; SB[r][1] = sp[64];
    }

    const float* pk  = kn + mb * DD + colA;
    const float* pa  = ab + mb * 256 + colA;
    const float* pm  = mn + mb * DD + colA;
    const float* pvA = qkv + mb * 512 + 256 + rbase + iA;
    const float* pv  = qkv + mb * 512 + 256 + rbase;
    const float* pq  = qn + mb * DD + rbase;
    const float* paB = ab + mb * 256 + lane;
    const float* pmB = mn + mb * DD + lane;
    __hip_bfloat16* po = pout + ((size_t)g * (BB * LL) + mb) * DD + lane;

    // current-step registers
    float ka[16], aa[16], ma[16];
    float4 vv4[2], qq4[2];
    float vA, aB0, aB1, mB0, mB1;
#pragma unroll
    for (int u = 0; u < 4; ++u) {
        float4 t;
        t = *(const float4*)(pk + 4 * u);
        ka[4*u] = t.x; ka[4*u+1] = t.y; ka[4*u+2] = t.z; ka[4*u+3] = t.w;
        t = *(const float4*)(pa + 4 * u);
        aa[4*u] = t.x; aa[4*u+1] = t.y; aa[4*u+2] = t.z; aa[4*u+3] = t.w;
        t = *(const float4*)(pm + 4 * u);
        ma[4*u] = t.x; ma[4*u+1] = t.y; ma[4*u+2] = t.z; ma[4*u+3] = t.w;
    }
    vv4[0] = *(const float4*)pv; vv4[1] = *(const float4*)(pv + 4);
    qq4[0] = *(const float4*)pq; qq4[1] = *(const float4*)(pq + 4);
    vA = *pvA;
    aB0 = paB[0]; aB1 = paB[64];
    mB0 = pmB[0]; mB1 = pmB[64];
    pk += DD; pa += 256; pm += DD; pvA += 512; pv += 512; pq += DD;
    paB += 256; pmB += DD;

#pragma unroll 2
    for (int t = 0; t < LL; ++t) {
        // ---- prefetch t+1 (final iter reads one row past end: stays in ws) --
        float kan[16], aan[16], man[16];
        float4 vv4n[2], qq4n[2];
        float vAn, aB0n, aB1n, mB0n, mB1n;
#pragma unroll
        for (int u = 0; u < 4; ++u) {
            float4 t4;
            t4 = *(const float4*)(pk + 4 * u);
            kan[4*u] = t4.x; kan[4*u+1] = t4.y; kan[4*u+2] = t4.z; kan[4*u+3] = t4.w;
            t4 = *(const float4*)(pa + 4 * u);
            aan[4*u] = t4.x; aan[4*u+1] = t4.y; aan[4*u+2] = t4.z; aan[4*u+3] = t4.w;
            t4 = *(const float4*)(pm + 4 * u);
            man[4*u] = t4.x; man[4*u+1] = t4.y; man[4*u+2] = t4.z; man[4*u+3] = t4.w;
        }
        vv4n[0] = *(const float4*)pv; vv4n[1] = *(const float4*)(pv + 4);
        qq4n[0] = *(const float4*)pq; qq4n[1] = *(const float4*)(pq + 4);
        vAn = *pvA;
        aB0n = paB[0]; aB1n = paB[64];
        mB0n = pmB[0]; mB1n = pmB[64];
        pk += DD; pa += 256; pm += DD; pvA += 512; pv += 512; pq += DD;
        paB += 256; pmB += DD;

        // ---- Sk dot (old S) + 3-stage butterfly over row group -------------
        float p = SA[0] * ka[0];
#pragma unroll
        for (int u = 1; u < 16; ++u) p = fmaf(SA[u], ka[u], p);
        p += __shfl_xor(p, 1);
        p += __shfl_xor(p, 2);
        p += __shfl_xor(p, 4);
        // broadcast all 8 rows' Sk to every lane
        float sk[8];
#pragma unroll
        for (int r = 0; r < 8; ++r) sk[r] = __shfl(p, r * 8 + c);

        // ---- A update: S = a*S + m*(v - a*Sk) -------------------------------
#pragma unroll
        for (int u = 0; u < 16; ++u) {
            float w = fmaf(-aa[u], p, vA);
            SA[u] = fmaf(ma[u], w, aa[u] * SA[u]);
        }

        // ---- B update + output partial --------------------------------------
        float vv[8] = {vv4[0].x, vv4[0].y, vv4[0].z, vv4[0].w,
                       vv4[1].x, vv4[1].y, vv4[1].z, vv4[1].w};
        float qv[8] = {qq4[0].x, qq4[0].y, qq4[0].z, qq4[0].w,
                       qq4[1].x, qq4[1].y, qq4[1].z, qq4[1].w};
        float po0 = 0.0f, po1 = 0.0f;
#pragma unroll
        for (int r = 0; r < 8; ++r) {
            float w0 = fmaf(-aB0, sk[r], vv[r]);
            SB[r][0] = fmaf(mB0, w0, aB0 * SB[r][0]);
            po0 = fmaf(qv[r], SB[r][0], po0);
            float w1 = fmaf(-aB1, sk[r], vv[r]);
            SB[r][1] = fmaf(mB1, w1, aB1 * SB[r][1]);
            po1 = fmaf(qv[r], SB[r][1], po1);
        }
        po[0]  = __float2bfloat16(po0);
        po[64] = __float2bfloat16(po1);
        po += DD;

        // ---- rotate prefetch -> current ------------------------------------
#pragma unroll
        for (int u = 0; u < 16; ++u) { ka[u] = kan[u]; aa[u] = aan[u]; ma[u] = man[u]; }
        vv4[0] = vv4n[0]; vv4[1] = vv4n[1];
        qq4[0] = qq4n[0]; qq4[1] = qq4n[1];
        vA = vAn; aB0 = aB0n; aB1 = aB1n; mB0 = mB0n; mB1 = mB1n;
    }

    {
        float* sp = sfin + ((size_t)b * DD + rbase + iA) * DD + colA;
#pragma unroll
        for (int u = 0; u < 4; ++u) {
            float4 o4 = {SA[4*u], SA[4*u+1], SA[4*u+2], SA[4*u+3]};
            *(float4*)(sp + 4 * u) = o4;
        }
    }
}

// ---------------------------------------------------------------------------
// out_core = silu(sum_g pout[g])   (pout bf16 -> fp32 accumulate)
// ---------------------------------------------------------------------------
__global__ __launch_bounds__(256) void combine_silu_kernel(
    const ushort* __restrict__ pout, float* __restrict__ oc)
{
    const size_t N = (size_t)BB * LL * DD;
    size_t idx = ((size_t)blockIdx.x * 256 + threadIdx.x) * 4;
    float s0 = 0, s1 = 0, s2 = 0, s3 = 0;
#pragma unroll
    for (int g = 0; g < GG; ++g) {
        uint2 u = *(const uint2*)(pout + g * N + idx);
        s0 += __uint_as_float((u.x & 0xffffu) << 16);
        s1 += __uint_as_float(u.x & 0xffff0000u);
        s2 += __uint_as_float((u.y & 0xffffu) << 16);
        s3 += __uint_as_float(u.y & 0xffff0000u);
    }
    float4 r;
    r.x = s0 / (1.0f + __expf(-s0));
    r.y = s1 / (1.0f + __expf(-s1));
    r.z = s2 / (1.0f + __expf(-s2));
    r.w = s3 / (1.0f + __expf(-s3));
    *(float4*)(oc + idx) = r;
}

// ---------------------------------------------------------------------------
// d_out = y * rsqrt(mean(y^2)+1e-6) * rms_w + residual. One wave per (b,l).
// ---------------------------------------------------------------------------
__global__ __launch_bounds__(256) void rms_res_kernel(
    const float* __restrict__ y, const float* __restrict__ res,
    const float* __restrict__ rmsw, float* __restrict__ out)
{
    const int tid = threadIdx.x;
    const int lane = tid & 63;
    const int wid = tid >> 6;
    const int m = blockIdx.x * 4 + wid;
    const int d0 = lane * 2;
    size_t o = (size_t)m * DD + d0;
    float2 yv = *(const float2*)(y + o);
    float ss = yv.x * yv.x + yv.y * yv.y;
#pragma unroll
    for (int msk = 1; msk <= 32; msk <<= 1) ss += __shfl_xor(ss, msk);
    float r = rsqrtf(ss * (1.0f / 128.0f) + 1e-6f);
    float2 rv = *(const float2*)(res + o);
    out[o]     = yv.x * r * rmsw[d0]     + rv.x;
    out[o + 1] = yv.y * r * rmsw[d0 + 1] + rv.y;
}

// ---------------------------------------------------------------------------
extern "C" void kernel_launch(void* const* d_in, const int* in_sizes, int n_in,
                              void* d_out, int out_size, void* d_ws, size_t ws_size,
                              hipStream_t stream)
{
    const float* x      = (const float*)d_in[0];
    const float* state  = (const float*)d_in[1];
    const float* W_in   = (const float*)d_in[2];
    const float* W_gate = (const float*)d_in[3];
    const float* W_out  = (const float*)d_in[4];
    const float* W_res  = (const float*)d_in[5];
    const float* qcw    = (const float*)d_in[6];
    const float* qcb    = (const float*)d_in[7];
    const float* kcw    = (const float*)d_in[8];
    const float* kcb    = (const float*)d_in[9];
    const float* rmsw   = (const float*)d_in[10];
    float* out  = (float*)d_out;
    float* sfin = out + (size_t)BB * LL * DD;

    const size_t M = (size_t)BB * LL;            // 16384
    float* ws = (float*)d_ws;
    float* qkv = ws;                 ws += M * 512;           // 33.5 MB
    float* abv = ws;                 ws += M * 256;           // 16.8 MB
    float* res = ws;                 ws += M * DD;            //  8.4 MB
    float* qnb = ws;                 ws += M * DD;
    float* knb = ws;                 ws += M * DD;
    float* mnb = ws;                 ws += M * DD;
    __hip_bfloat16* po = (__hip_bfloat16*)ws;                 // 67 MB (GG slices)
    // reuse (sequential stream order makes this safe):
    float* oc = qnb;   // combine output, after recurrence no longer reads qnb
    float* yb = knb;   // W_out GEMM output, after recurrence no longer reads knb

    dim3 blk(256);
    // qkv = x @ W_in^T  [M,512]
    gemm_kernel<<<dim3(M / 32, 8), blk, 0, stream>>>(x, 128, W_in, qkv, 512, 0);
    // residual = x @ W_res^T [M,128]
    gemm_kernel<<<dim3(M / 32, 2), blk, 0, stream>>>(x, 128, W_res, res, 128, 0);
    // alpha/beta = sigmoid(gate @ W_gate^T) [M,256]
    gemm_kernel<<<dim3(M / 32, 4), blk, 0, stream>>>(qkv + 384, 512, W_gate, abv, 256, 1);
    // q/k conv + sigmoid + l2norm (+ mn = beta*k)
    convnorm_kernel<<<dim3(M / 4), blk, 0, stream>>>(qkv, qcw, qcb, kcw, kcb, abv,
                                                     qnb, knb, mnb);
    // recurrence (barrier-free, one wave per WG)
    recur_kernel<<<dim3(BB * GG), dim3(64), 0, stream>>>(qnb, knb, mnb, abv, qkv,
                                                         state, po, sfin);
    // combine partials + silu
    combine_silu_kernel<<<dim3((M * DD) / 1024), blk, 0, stream>>>((const ushort*)po, oc);
    // y = out_core @ W_out^T
    gemm_kernel<<<dim3(M / 32, 2), blk, 0, stream>>>(oc, 128, W_out, yb, 128, 0);
    // RMS + residual -> d_out
    rms_res_kernel<<<dim3(M / 4), blk, 0, stream>>>(yb, res, rmsw, out);
}